// Round 7
// baseline (115.033 us; speedup 1.0000x reference)
//
#include <hip/hip_runtime.h>
#include <math.h>

#define NB 16
#define NA 3
#define NC 80
#define GS 4096                 // 64*64 spatial
#define NPOS (NB * NA * GS)     // 196608
#define CH_S 17                 // padded per-channel stride (16 pos + 1), odd -> spreads banks
#define WAVE_LDS (NC * CH_S)    // 1360 floats per wave

__device__ __forceinline__ float sigmoidf_(float v) {
    return 1.0f / (1.0f + __expf(-v));
}

// Wave-local transpose variant: one block = one (b,a,row); each of the 4 waves owns
// 16 positions x 80 cls channels and transposes through its PRIVATE LDS region.
// No __syncthreads() anywhere — only a wave-internal lgkmcnt drain between the LDS
// write and read halves, so global load/store streams interleave at wave granularity.
// NOTE (R4): nontemporal output stores are UNSAFE in this harness (poison-fill dirty
// L2 lines are incoherent with nt stores; post-timing validation diverged). Normal stores.
__global__ __launch_bounds__(256) void yolo_kernel(const float* __restrict__ x,
                                                   const float* __restrict__ anchors,
                                                   float* __restrict__ out) {
    __shared__ float lds[4 * WAVE_LDS];
    const int tid  = threadIdx.x;
    const int lane = tid & 63;
    const int w    = tid >> 6;          // wave id 0..3
    const int ba   = blockIdx.x >> 6;   // which (b,a), 0..47
    const int tile = blockIdx.x & 63;   // grid row i
    const int s0   = tile << 6;
    const float* __restrict__ xb = x + (size_t)ba * 85 * GS + s0;
    float* __restrict__ lw = lds + w * WAVE_LDS;
    const int pw = w << 4;              // wave's position base within the row

    // ---- cls reads: float4 loads (16 x 64B segments/instr; waves of a block cover
    // complementary halves of the same cache lines), sigmoid, LDS[ch][p] ----
    #pragma unroll
    for (int k = 0; k < 5; ++k) {
        const int e4 = lane + (k << 6);         // 0..319 = 80 ch x 4 float4-groups
        const int ch = e4 >> 2;
        const int g  = (e4 & 3) << 2;           // position offset within wave tile
        const float4 v = *reinterpret_cast<const float4*>(xb + (size_t)(5 + ch) * GS + pw + g);
        float* l = lw + ch * CH_S + g;
        l[0] = sigmoidf_(v.x);
        l[1] = sigmoidf_(v.y);
        l[2] = sigmoidf_(v.z);
        l[3] = sigmoidf_(v.w);
    }

    // ---- boxes + conf: lanes 0..15 of each wave handle the wave's 16 positions ----
    if (lane < 16) {
        const int p = pw + lane;                // position (column j) within the row
        const int t = ba * GS + s0 + p;         // global position index
        const float tx = xb[0 * GS + p];
        const float ty = xb[1 * GS + p];
        const float tw = xb[2 * GS + p];
        const float th = xb[3 * GS + p];
        const float tc = xb[4 * GS + p];
        const int a = ba % NA;
        const float aw = anchors[a * 2 + 0];    // anchors[a][0]*g0/scale(g0) = anchors[a][0]
        const float ah = anchors[a * 2 + 1];
        float4 box;
        box.x = (sigmoidf_(tx) + (float)tile) * (1.0f / 64.0f);  // grid_x = row i
        box.y = (sigmoidf_(ty) + (float)p)    * (1.0f / 64.0f);  // grid_y = col j
        box.z = __expf(tw) * aw;
        box.w = __expf(th) * ah;
        reinterpret_cast<float4*>(out)[t] = box;
        out[NPOS * 4 + t] = sigmoidf_(tc);
    }

    // wave-internal ordering: all LDS writes visible before transposed reads
    asm volatile("s_waitcnt lgkmcnt(0)" ::: "memory");
    __builtin_amdgcn_wave_barrier();

    // ---- cls writes: wave's 16x80 tile = contiguous 5120B, coalesced float4 ----
    float4* __restrict__ out4 =
        reinterpret_cast<float4*>(out + (size_t)NPOS * 5 + (size_t)(ba * GS + s0 + pw) * NC);
    #pragma unroll
    for (int k = 0; k < 5; ++k) {
        const int o4 = lane + (k << 6);         // 0..319
        const int o  = o4 * 4;
        const int p  = o / 80;                  // 0..15
        const int ch = o - p * 80;              // multiple of 4, <= 76
        float4 v;
        v.x = lw[(ch + 0) * CH_S + p];
        v.y = lw[(ch + 1) * CH_S + p];
        v.z = lw[(ch + 2) * CH_S + p];
        v.w = lw[(ch + 3) * CH_S + p];
        out4[o4] = v;
    }
}

extern "C" void kernel_launch(void* const* d_in, const int* in_sizes, int n_in,
                              void* d_out, int out_size, void* d_ws, size_t ws_size,
                              hipStream_t stream) {
    const float* x       = (const float*)d_in[0];
    const float* anchors = (const float*)d_in[1];
    float* out           = (float*)d_out;
    const int blocks = NB * NA * 64;    // 3072 blocks, one per (b,a,row)
    yolo_kernel<<<blocks, 256, 0, stream>>>(x, anchors, out);
}